// Round 1
// baseline (279.799 us; speedup 1.0000x reference)
//
#include <hip/hip_runtime.h>

#define S_DIM 2048
#define K_DIM 4096
#define O_DIM 4096
#define NNON  3968   // H - KEEPER
#define NB    31     // low-precision blocks

typedef __bf16 bf16x8 __attribute__((ext_vector_type(8)));
typedef float  f32x4  __attribute__((ext_vector_type(4)));

__device__ __forceinline__ unsigned short f2bf(float f) {
    union { float f; unsigned u; } v; v.f = f;
    unsigned r = v.u + 0x7FFFu + ((v.u >> 16) & 1u);   // round-to-nearest-even
    return (unsigned short)(r >> 16);
}

// A'[s,k] = bf16(x[s,k] * (k<NNON ? sc_lo[s,k/128] : sc_hi[s]))
__global__ __launch_bounds__(256) void scale_x(const float* __restrict__ x,
                                               const float* __restrict__ sc_lo,
                                               const float* __restrict__ sc_hi,
                                               unsigned short* __restrict__ A)
{
    int idx = blockIdx.x * 256 + threadIdx.x;  // over S*K/4, K/4 = 1024
    int s = idx >> 10;
    int k = (idx & 1023) << 2;                 // 4 elems never straddle a 128-block
    float4 v = ((const float4*)x)[idx];
    float sc = (k < NNON) ? sc_lo[s * NB + (k >> 7)] : sc_hi[s];
    ushort4 o;
    o.x = f2bf(v.x * sc); o.y = f2bf(v.y * sc);
    o.z = f2bf(v.z * sc); o.w = f2bf(v.w * sc);
    ((ushort4*)A)[idx] = o;
}

// B'[o,k] = bf16(weight[o,k] * (k<NNON ? scales[o, (k/128)*128] : keep[o]))
__global__ __launch_bounds__(256) void scale_w(const float* __restrict__ w,
                                               const float* __restrict__ scales,
                                               const float* __restrict__ keep,
                                               unsigned short* __restrict__ B)
{
    int idx = blockIdx.x * 256 + threadIdx.x;  // over O*K/4
    int o = idx >> 10;
    int k = (idx & 1023) << 2;
    float4 v = ((const float4*)w)[idx];
    float sc = (k < NNON) ? scales[(size_t)o * NNON + ((k >> 7) << 7)] : keep[o];
    ushort4 r;
    r.x = f2bf(v.x * sc); r.y = f2bf(v.y * sc);
    r.z = f2bf(v.z * sc); r.w = f2bf(v.w * sc);
    ((ushort4*)B)[idx] = r;
}

// m97-structure NT GEMM: A [M,K] bf16, B [N,K] bf16 (B^T layout), C [M,N] f32.
// 128x128 block tile, BK=32, 4 waves in 2x2, each wave 4x4 of 16x16x32 MFMAs.
#define BM 128
#define BN 128
#define BK 32

__global__ __launch_bounds__(256) void gemm_bt(const unsigned short* __restrict__ A,
                                               const unsigned short* __restrict__ B,
                                               float* __restrict__ C)
{
    __shared__ unsigned short As[BM * BK];   // 8 KB, row-major [row][k], no pad
    __shared__ unsigned short Bs[BN * BK];   // 8 KB

    const int tid  = threadIdx.x;
    const int wave = tid >> 6;
    const int lane = tid & 63;
    const int quad = lane >> 4;
    const int l16  = lane & 15;
    const int bm = blockIdx.y * BM;
    const int bn = blockIdx.x * BN;
    const int wm = (wave >> 1) * 64;
    const int wn = (wave & 1) * 64;

    // staging: each wave fills 2 chunks of 16 rows x 32 cols (1024 B) per tile.
    // lane -> row chunk*16 + lane/4, col (lane%4)*8; LDS dest is wave-uniform
    // base + lane*16 (global_load_lds semantics), matching row-major [row][k].
    const int ar0 = wave * 32 + (lane >> 2);
    const int ac  = (lane & 3) * 8;

    f32x4 acc[4][4];
    #pragma unroll
    for (int i = 0; i < 4; ++i)
        #pragma unroll
        for (int j = 0; j < 4; ++j)
            acc[i][j] = (f32x4){0.f, 0.f, 0.f, 0.f};

    for (int k0 = 0; k0 < K_DIM; k0 += BK) {
        __syncthreads();   // previous tile's MFMAs done before overwrite
        #pragma unroll
        for (int c = 0; c < 2; ++c) {
            const int row = ar0 + c * 16;
            __builtin_amdgcn_global_load_lds(
                (__attribute__((address_space(1))) unsigned int*)(A + (size_t)(bm + row) * K_DIM + k0 + ac),
                (__attribute__((address_space(3))) unsigned int*)(&As[(wave * 2 + c) * 512]),
                16, 0, 0);
            __builtin_amdgcn_global_load_lds(
                (__attribute__((address_space(1))) unsigned int*)(B + (size_t)(bn + row) * K_DIM + k0 + ac),
                (__attribute__((address_space(3))) unsigned int*)(&Bs[(wave * 2 + c) * 512]),
                16, 0, 0);
        }
        __syncthreads();   // compiler emits s_waitcnt vmcnt(0) before barrier

        bf16x8 af[4], bfr[4];
        #pragma unroll
        for (int i = 0; i < 4; ++i)
            af[i] = *(const bf16x8*)(&As[(wm + i * 16 + l16) * BK + quad * 8]);
        #pragma unroll
        for (int j = 0; j < 4; ++j)
            bfr[j] = *(const bf16x8*)(&Bs[(wn + j * 16 + l16) * BK + quad * 8]);
        #pragma unroll
        for (int i = 0; i < 4; ++i)
            #pragma unroll
            for (int j = 0; j < 4; ++j)
                acc[i][j] = __builtin_amdgcn_mfma_f32_16x16x32_bf16(af[i], bfr[j], acc[i][j], 0, 0, 0);
    }

    // C/D layout (m89-verified): col = lane&15, row = quad*4 + reg
    #pragma unroll
    for (int i = 0; i < 4; ++i)
        #pragma unroll
        for (int j = 0; j < 4; ++j) {
            const int col = bn + wn + j * 16 + l16;
            #pragma unroll
            for (int r = 0; r < 4; ++r) {
                const int row = bm + wm + i * 16 + quad * 4 + r;
                C[(size_t)row * O_DIM + col] = acc[i][j][r];
            }
        }
}

extern "C" void kernel_launch(void* const* d_in, const int* in_sizes, int n_in,
                              void* d_out, int out_size, void* d_ws, size_t ws_size,
                              hipStream_t stream) {
    const float* x      = (const float*)d_in[0];
    const float* weight = (const float*)d_in[1];  // [O, K]
    const float* scales = (const float*)d_in[2];  // [O, NNON]
    const float* keep   = (const float*)d_in[3];  // [O, 1]
    const float* sc_lo  = (const float*)d_in[4];  // [S, NB]
    const float* sc_hi  = (const float*)d_in[5];  // [S, 1]
    // d_in[6], d_in[7] (inp_base_lo/hi) unused by reference

    // workspace: A' 16 MB @ 0, B' 32 MB @ 16 MB (needs 48 MB of d_ws)
    unsigned short* A = (unsigned short*)d_ws;
    unsigned short* B = A + (size_t)S_DIM * K_DIM;

    scale_x<<<(S_DIM * K_DIM / 4) / 256, 256, 0, stream>>>(x, sc_lo, sc_hi, A);
    scale_w<<<(O_DIM * K_DIM / 4) / 256, 256, 0, stream>>>(weight, scales, keep, B);

    dim3 grid(O_DIM / BN, S_DIM / BM);
    gemm_bt<<<grid, 256, 0, stream>>>(A, B, (float*)d_out);
}

// Round 2
// 259.556 us; speedup vs baseline: 1.0780x; 1.0780x over previous
//
#include <hip/hip_runtime.h>

#define S_DIM 2048
#define K_DIM 4096
#define O_DIM 4096
#define NNON  3968   // H - KEEPER
#define NB    31     // low-precision blocks

typedef __bf16 bf16x8 __attribute__((ext_vector_type(8)));
typedef float  f32x4  __attribute__((ext_vector_type(4)));

__device__ __forceinline__ unsigned short f2bf(float f) {
    union { float f; unsigned u; } v; v.f = f;
    unsigned r = v.u + 0x7FFFu + ((v.u >> 16) & 1u);   // round-to-nearest-even
    return (unsigned short)(r >> 16);
}

// A'[s,k] = bf16(x[s,k] * (k<NNON ? sc_lo[s,k/128] : sc_hi[s]))
__global__ __launch_bounds__(256) void scale_x(const float* __restrict__ x,
                                               const float* __restrict__ sc_lo,
                                               const float* __restrict__ sc_hi,
                                               unsigned short* __restrict__ A)
{
    int idx = blockIdx.x * 256 + threadIdx.x;  // over S*K/4, K/4 = 1024
    int s = idx >> 10;
    int k = (idx & 1023) << 2;                 // 4 elems never straddle a 128-block
    float4 v = ((const float4*)x)[idx];
    float sc = (k < NNON) ? sc_lo[s * NB + (k >> 7)] : sc_hi[s];
    ushort4 o;
    o.x = f2bf(v.x * sc); o.y = f2bf(v.y * sc);
    o.z = f2bf(v.z * sc); o.w = f2bf(v.w * sc);
    ((ushort4*)A)[idx] = o;
}

// B'[o,k] = bf16(weight[o,k] * (k<NNON ? scales[o, (k/128)*128] : keep[o]))
__global__ __launch_bounds__(256) void scale_w(const float* __restrict__ w,
                                               const float* __restrict__ scales,
                                               const float* __restrict__ keep,
                                               unsigned short* __restrict__ B)
{
    int idx = blockIdx.x * 256 + threadIdx.x;  // over O*K/4
    int o = idx >> 10;
    int k = (idx & 1023) << 2;
    float4 v = ((const float4*)w)[idx];
    float sc = (k < NNON) ? scales[(size_t)o * NNON + ((k >> 7) << 7)] : keep[o];
    ushort4 r;
    r.x = f2bf(v.x * sc); r.y = f2bf(v.y * sc);
    r.z = f2bf(v.z * sc); r.w = f2bf(v.w * sc);
    ((ushort4*)B)[idx] = r;
}

// NT GEMM: A [M,K] bf16, B [N,K] bf16 (B^T layout), C [M,N] f32.
// 128x128 block tile, BK=64 (half the barriers of m97's BK=32), 4 waves 2x2,
// each wave 4x4 of 16x16x32 MFMAs x 2 k-steps per staging tile.
// LDS layout XOR-swizzled: 16B chunk at logical (row, c) stored at chunk
// position c ^ (row & 7)  -> ds_read_b128 lanes spread over all 8 bank groups
// (2-way aliasing only = free). Swizzle is applied on the *global source
// address* during global_load_lds staging (LDS dest is fixed lane*16B).
#define BM 128
#define BN 128
#define BK 64

__global__ __launch_bounds__(256) void gemm_bt(const unsigned short* __restrict__ A,
                                               const unsigned short* __restrict__ B,
                                               float* __restrict__ C)
{
    __shared__ unsigned short As[BM * BK];   // 16 KB
    __shared__ unsigned short Bs[BN * BK];   // 16 KB

    const int tid  = threadIdx.x;
    const int wave = tid >> 6;
    const int lane = tid & 63;
    const int quad = lane >> 4;
    const int l16  = lane & 15;
    const int bm = blockIdx.y * BM;
    const int bn = blockIdx.x * BN;
    const int wm = (wave >> 1) * 64;
    const int wn = (wave & 1) * 64;

    // staging: per wave, 4 chunks of 8 rows x 64 cols (1 KB) per matrix per tile.
    // lane -> local row lane>>3, stored chunk lane&7; global col chunk is
    // (lane&7) ^ (row&7) to realize the swizzle.
    const int srow = (lane >> 3);                       // 0..7 within chunk
    const int scol = (((lane & 7) ^ (srow & 7)) << 3);  // element offset 0..56
    const int swz  = (l16 & 7);                         // reader-side XOR key

    f32x4 acc[4][4];
    #pragma unroll
    for (int i = 0; i < 4; ++i)
        #pragma unroll
        for (int j = 0; j < 4; ++j)
            acc[i][j] = (f32x4){0.f, 0.f, 0.f, 0.f};

    for (int k0 = 0; k0 < K_DIM; k0 += BK) {
        __syncthreads();   // previous tile's reads done before overwrite
        #pragma unroll
        for (int c = 0; c < 4; ++c) {
            const int row = wave * 32 + c * 8 + srow;
            __builtin_amdgcn_global_load_lds(
                (__attribute__((address_space(1))) unsigned int*)(A + (size_t)(bm + row) * K_DIM + k0 + scol),
                (__attribute__((address_space(3))) unsigned int*)(&As[(wave * 4 + c) * 512]),
                16, 0, 0);
            __builtin_amdgcn_global_load_lds(
                (__attribute__((address_space(1))) unsigned int*)(B + (size_t)(bn + row) * K_DIM + k0 + scol),
                (__attribute__((address_space(3))) unsigned int*)(&Bs[(wave * 4 + c) * 512]),
                16, 0, 0);
        }
        __syncthreads();   // compiler emits s_waitcnt vmcnt(0) before barrier

        #pragma unroll
        for (int ks = 0; ks < 2; ++ks) {
            bf16x8 af[4], bfr[4];
            #pragma unroll
            for (int i = 0; i < 4; ++i)
                af[i] = *(const bf16x8*)(&As[(wm + i * 16 + l16) * BK + (((ks * 4 + quad) ^ swz) << 3)]);
            #pragma unroll
            for (int j = 0; j < 4; ++j)
                bfr[j] = *(const bf16x8*)(&Bs[(wn + j * 16 + l16) * BK + (((ks * 4 + quad) ^ swz) << 3)]);
            #pragma unroll
            for (int i = 0; i < 4; ++i)
                #pragma unroll
                for (int j = 0; j < 4; ++j)
                    acc[i][j] = __builtin_amdgcn_mfma_f32_16x16x32_bf16(af[i], bfr[j], acc[i][j], 0, 0, 0);
        }
    }

    // C/D layout (m89-verified): col = lane&15, row = quad*4 + reg
    #pragma unroll
    for (int i = 0; i < 4; ++i)
        #pragma unroll
        for (int j = 0; j < 4; ++j) {
            const int col = bn + wn + j * 16 + l16;
            #pragma unroll
            for (int r = 0; r < 4; ++r) {
                const int row = bm + wm + i * 16 + quad * 4 + r;
                C[(size_t)row * O_DIM + col] = acc[i][j][r];
            }
        }
}

extern "C" void kernel_launch(void* const* d_in, const int* in_sizes, int n_in,
                              void* d_out, int out_size, void* d_ws, size_t ws_size,
                              hipStream_t stream) {
    const float* x      = (const float*)d_in[0];
    const float* weight = (const float*)d_in[1];  // [O, K]
    const float* scales = (const float*)d_in[2];  // [O, NNON]
    const float* keep   = (const float*)d_in[3];  // [O, 1]
    const float* sc_lo  = (const float*)d_in[4];  // [S, NB]
    const float* sc_hi  = (const float*)d_in[5];  // [S, 1]
    // d_in[6], d_in[7] (inp_base_lo/hi) unused by reference

    // workspace: A' 16 MB @ 0, B' 32 MB @ 16 MB (needs 48 MB of d_ws)
    unsigned short* A = (unsigned short*)d_ws;
    unsigned short* B = A + (size_t)S_DIM * K_DIM;

    scale_x<<<(S_DIM * K_DIM / 4) / 256, 256, 0, stream>>>(x, sc_lo, sc_hi, A);
    scale_w<<<(O_DIM * K_DIM / 4) / 256, 256, 0, stream>>>(weight, scales, keep, B);

    dim3 grid(O_DIM / BN, S_DIM / BM);
    gemm_bt<<<grid, 256, 0, stream>>>(A, B, (float*)d_out);
}